// Round 8
// baseline (82.541 us; speedup 1.0000x reference)
//
#include <hip/hip_runtime.h>
#include <math.h>

#pragma clang fp contract(off)

#define HH 96
#define WW 96
#define NV 9120          // 95*96 vertical candidates (== 96*95 horizontal)
#define NC 18240         // candidates per image
#define NPIX 9216
#define ABLK 2280        // NC/8: 8 32-lane point-groups per 256-thread block
#define PBLK 144         // NPIX/64 pixel blocks (64 threads each)
#define SENT_D 3.4e38f
#define SENT_J 0x7fffffff

// zero-crossing point for candidate u (bit-exact reference formulas)
__device__ __forceinline__ void zc_point(const float* __restrict__ S, int u,
                                         float& r, float& c, int& m){
#pragma clang fp contract(off)
  float v1, v2;
  if (u < NV){
    int i0 = u / WW, j = u % WW;
    v1 = S[i0*WW+j]; v2 = S[(i0+1)*WW+j];
    float a1 = fabsf(v1), a2 = fabsf(v2);
    float den = (a1 + a2) + 1e-8f;      // left-assoc as reference
    float a = a1 / den;
    float i0f = (float)i0;
    r = (v1 == 0.0f) ? i0f : ((v2 == 0.0f) ? (i0f + 1.0f) : (i0f + a));
    c = (float)j;
  } else {
    int u2 = u - NV;
    int i = u2 / (WW-1), j0 = u2 % (WW-1);
    v1 = S[i*WW+j0]; v2 = S[i*WW+j0+1];
    float a1 = fabsf(v1), a2 = fabsf(v2);
    float den = (a1 + a2) + 1e-8f;
    float b = a1 / den;
    float j0f = (float)j0;
    c = (v1 == 0.0f) ? j0f : ((v2 == 0.0f) ? (j0f + 1.0f) : (j0f + b));
    r = (float)i;
  }
  m = (v1 == 0.0f) || (v2 == 0.0f) || ((v1*v2) < 0.0f);
}

// central-difference normal of PR at (i,j) — bit-exact reference
__device__ __forceinline__ float2 normal_at(const float* __restrict__ PR,
                                            int i, int j){
#pragma clang fp contract(off)
  float gr, gc;
  if (i == 0)         gr = PR[WW+j] - PR[j];
  else if (i == HH-1) gr = PR[(HH-1)*WW+j] - PR[(HH-2)*WW+j];
  else                gr = (PR[(i+1)*WW+j] - PR[(i-1)*WW+j]) / 2.0f;
  if (j == 0)         gc = PR[i*WW+1] - PR[i*WW];
  else if (j == WW-1) gc = PR[i*WW+WW-1] - PR[i*WW+WW-2];
  else                gc = (PR[i*WW+j+1] - PR[i*WW+j-1]) / 2.0f;
  return make_float2(gr, gc);
}

// build cell (ci,cj)'s <=4 gt candidates from GT and lex-(d2,jg)-min update.
// enumeration order irrelevant: lex min over (d2, jg) is a total order.
__device__ __forceinline__ void scan_cell(int ci, int cj,
    float rp, float cp, float sp, const float* __restrict__ GT,
    float& best, int& bjg, float& brg, float& bcg){
#pragma clang fp contract(off)
  // vertical sources i0 = ci-1, ci (column cj)
  for (int s = 0; s < 2; ++s){
    int i0 = ci - 1 + s;
    if (i0 < 0 || i0 > HH-2) continue;
    float v1 = GT[i0*WW+cj], v2 = GT[(i0+1)*WW+cj];
    int m = (v1 == 0.0f) || (v2 == 0.0f) || ((v1*v2) < 0.0f);
    if (!m) continue;
    float a1 = fabsf(v1), a2 = fabsf(v2);
    float den = (a1 + a2) + 1e-8f;
    float a = a1 / den;
    float i0f = (float)i0;
    float r = (v1 == 0.0f) ? i0f : ((v2 == 0.0f) ? (i0f + 1.0f) : (i0f + a));
    if ((int)floorf(r) != ci) continue;            // lands in this cell row
    float c = (float)cj;
    float sg = (r*r) + (c*c);                      // matches (gp**2).sum(1)
    int jg = i0*WW + cj;
    float cross = fmaf(cp, c, rp*r);               // same bits as brute force
    float d2 = (sp + sg) - (2.0f*cross);
    d2 = fmaxf(d2, 0.0f);
    if ((d2 < best) || ((d2 == best) && (jg < bjg))){
      best = d2; bjg = jg; brg = r; bcg = c;
    }
  }
  // horizontal sources j0 = cj-1, cj (row ci)
  for (int s = 0; s < 2; ++s){
    int j0 = cj - 1 + s;
    if (j0 < 0 || j0 > WW-2) continue;
    float v1 = GT[ci*WW+j0], v2 = GT[ci*WW+j0+1];
    int m = (v1 == 0.0f) || (v2 == 0.0f) || ((v1*v2) < 0.0f);
    if (!m) continue;
    float a1 = fabsf(v1), a2 = fabsf(v2);
    float den = (a1 + a2) + 1e-8f;
    float b = a1 / den;
    float j0f = (float)j0;
    float c = (v1 == 0.0f) ? j0f : ((v2 == 0.0f) ? (j0f + 1.0f) : (j0f + b));
    if ((int)floorf(c) != cj) continue;            // lands in this cell col
    float r = (float)ci;
    float sg = (r*r) + (c*c);
    int jg = NV + ci*(WW-1) + j0;
    float cross = fmaf(cp, c, rp*r);
    float d2 = (sp + sg) - (2.0f*cross);
    d2 = fmaxf(d2, 0.0f);
    if ((d2 < best) || ((d2 == best) && (jg < bjg))){
      best = d2; bjg = jg; brg = r; bcg = c;
    }
  }
}

// ring offset for chebyshev ring R, perimeter index q in [0, 8R)
__device__ __forceinline__ void ring_off(int R, int q, int& dr, int& dc){
  int side = 2*R + 1;
  if (q < side){ dr = -R; dc = q - R; }
  else if (q < 2*side){ dr = R; dc = q - side - R; }
  else {
    int q2 = q - 2*side, half = side - 2;
    if (q2 < half){ dr = q2 - R + 1; dc = -R; }
    else          { dr = q2 - half - R + 1; dc = R; }
  }
}

// ---- K1: 32-lane-group-per-point NN; lane0 computes point + epilogue -----
__global__ __launch_bounds__(256) void k_nndot(
    const float* __restrict__ PR, const float* __restrict__ GT,
    float* __restrict__ dotA, double* __restrict__ pvPart, int* finCnt){
#pragma clang fp contract(off)
  int l = threadIdx.x & 31;
  int g = threadIdx.x >> 5;            // 8 groups per block
  int k = blockIdx.x*8 + g;            // grid is exactly NC/8 blocks
  if (blockIdx.x == 0 && threadIdx.x == 0) *finCnt = 0;
  // lane 0 of each group computes the point; broadcast coords to the group
  float rp = 0.0f, cp = 0.0f; int m = 0;
  if (l == 0) zc_point(PR, k, rp, cp, m);
  rp = __shfl(rp, 0, 32);
  cp = __shfl(cp, 0, 32);
  float sp = (rp*rp) + (cp*cp);        // matches (pr_pts**2).sum(1)
  int fr = (int)floorf(rp), fc = (int)floorf(cp);
  // phase 1: inner 5x5 (radius 2), one cell per lane, one round
  float best = SENT_D, brg = 0.0f, bcg = 0.0f; int bjg = SENT_J;
  if (l < 25){
    int ci = fr + l/5 - 2, cj = fc + l%5 - 2;
    if (ci >= 0 && ci < HH && cj >= 0 && cj < WW)
      scan_cell(ci, cj, rp, cp, sp, GT, best, bjg, brg, bcg);
  }
  for (int off = 16; off; off >>= 1){  // lex butterfly within 32-lane group
    float ob = __shfl_xor(best, off, 64);
    int   oj = __shfl_xor(bjg,  off, 64);
    float orr = __shfl_xor(brg, off, 64);
    float oc = __shfl_xor(bcg, off, 64);
    if ((ob < best) || ((ob == best) && (oj < bjg))){
      best = ob; bjg = oj; brg = orr; bcg = oc;
    }
  }
  // outside radius 2 true d2 > 4 (computed >= 4-6e-6): skip if best <= 3.9999
  if (best > 3.9999f){                 // group-uniform after reduce
    for (int q = l; q < 56; q += 32){  // rings 3 (24) + 4 (32)
      int dr2, dc2;
      if (q < 24) ring_off(3, q, dr2, dc2);
      else        ring_off(4, q-24, dr2, dc2);
      int ci = fr + dr2, cj = fc + dc2;
      if (ci >= 0 && ci < HH && cj >= 0 && cj < WW)
        scan_cell(ci, cj, rp, cp, sp, GT, best, bjg, brg, bcg);
    }
    for (int off = 16; off; off >>= 1){
      float ob = __shfl_xor(best, off, 64);
      int   oj = __shfl_xor(bjg,  off, 64);
      float orr = __shfl_xor(brg, off, 64);
      float oc = __shfl_xor(bcg, off, 64);
      if ((ob < best) || ((ob == best) && (oj < bjg))){
        best = ob; bjg = oj; brg = orr; bcg = oc;
      }
    }
  }
  // epilogue: lane 0 only (exec-masked lanes issue no loads)
  __shared__ float sdot[8];
  __shared__ double sb[8];
  if (l == 0){
    int r0 = fr; if (r0 < 0) r0 = 0; if (r0 > HH-1) r0 = HH-1;
    int c0 = fc; if (c0 < 0) c0 = 0; if (c0 > WW-1) c0 = WW-1;
    int r1 = r0 + 1; if (r1 > HH-1) r1 = HH-1;
    int c1 = c0 + 1; if (c1 > WW-1) c1 = WW-1;
    float2 na = normal_at(PR, r0, c0), nb = normal_at(PR, r0, c1);
    float2 ncn = normal_at(PR, r1, c0), nd = normal_at(PR, r1, c1);
    float pa = PR[r0*WW+c0], pb = PR[r0*WW+c1];
    float pc = PR[r1*WW+c0], pd = PR[r1*WW+c1];
    float ar = rp - (float)r0, ac = cp - (float)c0;
    float omr = 1.0f - ar, omc = 1.0f - ac;
    float wa = omr*omc, wb = omr*ac, wc = ar*omc, wd = ar*ac;
    float nr = (((na.x*wa) + (nb.x*wb)) + (ncn.x*wc)) + (nd.x*wd);
    float nc = (((na.y*wa) + (nb.y*wb)) + (ncn.y*wc)) + (nd.y*wd);
    float nrm = sqrtf((nr*nr) + (nc*nc));
    float den = nrm + 1e-8f;
    float nru = nr / den, ncu = nc / den;
    float dr = brg - rp, dc = bcg - cp;  // winner coords from reduction
    float dotv = (dr*nru) + (dc*ncu);
    int contrib = m && (best <= 9.0f);
    float vals = (((pa*wa) + (pb*wb)) + (pc*wc)) + (pd*wd);
    sdot[g] = contrib ? dotv : 0.0f;
    sb[g] = m ? (double)vals : 0.0;
  }
  __syncthreads();
  if (threadIdx.x < 8)                  // coalesced dotA store, 8 consecutive k
    dotA[blockIdx.x*8 + threadIdx.x] = sdot[threadIdx.x];
  if (threadIdx.x == 0){
    double acc = 0.0;
    for (int q = 0; q < 8; ++q) acc += sb[q];
    pvPart[blockIdx.x] = acc;
  }
}

// ---- K2: ordered scatter (coords recomputed inline) + last-block final ----
__global__ __launch_bounds__(64) void k_pixfinal(
    const float* __restrict__ PR, const float* __restrict__ dotA,
    const double* __restrict__ pvPart,
    float* tmp, int* finCnt, float* out){
#pragma clang fp contract(off)
  int p = blockIdx.x*64 + threadIdx.x;    // exactly NPIX threads
  int i = p / WW, j = p % WW;
  float s = 0.0f;
  // pass1 vertical: wa = (1-ar) at (r0, j)
  for (int i0 = i-1; i0 <= i; ++i0){
    if (i0 < 0 || i0 > HH-2) continue;
    float v1 = PR[i0*WW+j], v2 = PR[(i0+1)*WW+j];
    float a1 = fabsf(v1), a2 = fabsf(v2);
    float dn = (a1 + a2) + 1e-8f;
    float a = a1 / dn;
    float i0f = (float)i0;
    float r = (v1 == 0.0f) ? i0f : ((v2 == 0.0f) ? (i0f + 1.0f) : (i0f + a));
    int r0 = (int)floorf(r);
    if (r0 == i){
      float ar = r - (float)r0;
      float w = 1.0f - ar;
      s = s + (dotA[i0*WW+j] * w);
    }
  }
  // pass1 horizontal: wa = (1-ac) at (i, c0)
  for (int j0 = j-1; j0 <= j; ++j0){
    if (j0 < 0 || j0 > WW-2) continue;
    float v1 = PR[i*WW+j0], v2 = PR[i*WW+j0+1];
    float a1 = fabsf(v1), a2 = fabsf(v2);
    float dn = (a1 + a2) + 1e-8f;
    float b = a1 / dn;
    float j0f = (float)j0;
    float c = (v1 == 0.0f) ? j0f : ((v2 == 0.0f) ? (j0f + 1.0f) : (j0f + b));
    int c0 = (int)floorf(c);
    if (c0 == j){
      float ac = c - (float)c0;
      float w = 1.0f - ac;
      s = s + (dotA[NV + i*(WW-1) + j0] * w);
    }
  }
  // pass2 horizontal: wb = ac at (i, c0+1)
  for (int j0 = j-2; j0 <= j-1; ++j0){
    if (j0 < 0 || j0 > WW-2) continue;
    float v1 = PR[i*WW+j0], v2 = PR[i*WW+j0+1];
    float a1 = fabsf(v1), a2 = fabsf(v2);
    float dn = (a1 + a2) + 1e-8f;
    float b = a1 / dn;
    float j0f = (float)j0;
    float c = (v1 == 0.0f) ? j0f : ((v2 == 0.0f) ? (j0f + 1.0f) : (j0f + b));
    int c0 = (int)floorf(c);
    if (c0 == j-1){
      float ac = c - (float)c0;
      s = s + (dotA[NV + i*(WW-1) + j0] * ac);
    }
  }
  // pass3 vertical: wc = ar at (r0+1, j)
  for (int i0 = i-2; i0 <= i-1; ++i0){
    if (i0 < 0 || i0 > HH-2) continue;
    float v1 = PR[i0*WW+j], v2 = PR[(i0+1)*WW+j];
    float a1 = fabsf(v1), a2 = fabsf(v2);
    float dn = (a1 + a2) + 1e-8f;
    float a = a1 / dn;
    float i0f = (float)i0;
    float r = (v1 == 0.0f) ? i0f : ((v2 == 0.0f) ? (i0f + 1.0f) : (i0f + a));
    int r0 = (int)floorf(r);
    if (r0 == i-1){
      float ar = r - (float)r0;
      s = s + (dotA[i0*WW+j] * ar);
    }
  }
  tmp[p] = PR[p] * s;
  // release tmp writes, count this block done
  __threadfence();
  __syncthreads();
  __shared__ int lastFlag;
  if (threadIdx.x == 0){
    int old = atomicAdd(finCnt, 1);      // device-scope
    lastFlag = (old == PBLK-1);
  }
  __syncthreads();
  if (!lastFlag) return;
  __threadfence();                       // acquire: see all blocks' tmp
  // numpy pairwise sum: identical 128-leaf x 72 tree, 64 threads, 2 slots each
  __shared__ float buf[128];
  __shared__ double dbuf[64];
  int t = threadIdx.x;                   // 0..63
  for (int leaf = t; leaf < 128; leaf += 64){
    const float4* a4 = (const float4*)(tmp + leaf*72);
    float4 x = a4[0], y = a4[1];
    float q0=x.x, q1=x.y, q2=x.z, q3=x.w, q4=y.x, q5=y.y, q6=y.z, q7=y.w;
    for (int i4 = 2; i4 < 18; i4 += 2){
      float4 u = a4[i4], v = a4[i4+1];
      q0 += u.x; q1 += u.y; q2 += u.z; q3 += u.w;
      q4 += v.x; q5 += v.y; q6 += v.z; q7 += v.w;
    }
    buf[leaf] = ((q0+q1)+(q2+q3)) + ((q4+q5)+(q6+q7));
  }
  double pv = 0.0;
  for (int idx = t; idx < ABLK; idx += 64) pv += pvPart[idx];
  dbuf[t] = pv;
  __syncthreads();
  for (int st = 1; st < 128; st <<= 1){  // same combine tree, 2 slots/thread
    for (int idx = t; idx < 128; idx += 64){
      if ((idx & (2*st - 1)) == 0 && idx + st < 128)
        buf[idx] = buf[idx] + buf[idx+st];
    }
    if (st < 64 && (t & (2*st - 1)) == 0) dbuf[t] = dbuf[t] + dbuf[t+st];
    __syncthreads();
  }
  if (t == 0) out[0] = buf[0] + (float)dbuf[0];
}

extern "C" void kernel_launch(void* const* d_in, const int* in_sizes, int n_in,
                              void* d_out, int out_size, void* d_ws, size_t ws_size,
                              hipStream_t stream){
  const float* pred = (const float*)d_in[0];
  const float* gt   = (const float*)d_in[1];
  float* out = (float*)d_out;

  char* w = (char*)d_ws;
  double* pvPart = (double*)w;                 w += (size_t)ABLK*sizeof(double);
  float*  dotA   = (float*)w;                  w += (size_t)NC*sizeof(float);
  float*  tmp    = (float*)w;                  w += (size_t)NPIX*sizeof(float);
  int*    finCnt = (int*)w;

  k_nndot<<<dim3(ABLK), dim3(256), 0, stream>>>(pred, gt, dotA, pvPart, finCnt);
  k_pixfinal<<<dim3(PBLK), dim3(64), 0, stream>>>(pred, dotA, pvPart,
                                                  tmp, finCnt, out);
}

// Round 9
// 75.013 us; speedup vs baseline: 1.1004x; 1.1004x over previous
//
#include <hip/hip_runtime.h>
#include <math.h>

#pragma clang fp contract(off)

#define HH 96
#define WW 96
#define NV 9120          // 95*96 vertical candidates (== 96*95 horizontal)
#define NC 18240         // candidates per image
#define NPIX 9216
#define NCELL 9216       // 96x96 spatial hash cells
#define SLOTS 4          // deterministic bound: <=4 gt crossings per cell
#define NBLK2 1140       // NC/16 point-blocks for k_nndot (16 lanes/point)
#define PBLK 72          // 9216/128 pixel blocks
#define SENT_D 3.4e38f
#define SENT_J 0x7fffffff

// ---- K1: split work items: [0,NPIX) normals+grid, [NPIX,NPIX+NC) pred ----
__global__ __launch_bounds__(256) void k_prep(
    const float* __restrict__ PR, const float* __restrict__ GT,
    float2* __restrict__ N2, float4* prQ,
    float4* cells, int* finCnt){
#pragma clang fp contract(off)
  int t = blockIdx.x*256 + threadIdx.x;
  if (t == 0) *finCnt = 0;
  if (t < NPIX){
    int i = t / WW, j = t % WW;
    // central-difference normals of pred
    float gr, gc;
    if (i == 0)         gr = PR[WW+j] - PR[j];
    else if (i == HH-1) gr = PR[(HH-1)*WW+j] - PR[(HH-2)*WW+j];
    else                gr = (PR[(i+1)*WW+j] - PR[(i-1)*WW+j]) / 2.0f;
    if (j == 0)         gc = PR[i*WW+1] - PR[i*WW];
    else if (j == WW-1) gc = PR[i*WW+WW-1] - PR[i*WW+WW-2];
    else                gc = (PR[i*WW+j+1] - PR[i*WW+j-1]) / 2.0f;
    N2[t] = make_float2(gr, gc);
    // grid build for cell (i,j): <=4 deterministic sources, sentinel-padded
    int cnt = 0;
    float4 slot[SLOTS];
    for (int s = 0; s < 2; ++s){              // vertical sources i0=i-1, i
      int i0 = i - 1 + s;
      if (i0 >= 0 && i0 <= HH-2){
        float v1 = GT[i0*WW+j], v2 = GT[(i0+1)*WW+j];
        int m = (v1 == 0.0f) || (v2 == 0.0f) || ((v1*v2) < 0.0f);
        if (m){
          float a1 = fabsf(v1), a2 = fabsf(v2);
          float den = (a1 + a2) + 1e-8f;      // left-assoc as reference
          float a = a1 / den;
          float i0f = (float)i0;
          float r = (v1 == 0.0f) ? i0f : ((v2 == 0.0f) ? (i0f + 1.0f) : (i0f + a));
          if ((int)floorf(r) == i){           // lands in this cell row
            float c = (float)j;
            float sg = (r*r) + (c*c);         // matches (gp**2).sum(1)
            slot[cnt++] = make_float4(r, c, sg, __int_as_float(i0*WW+j));
          }
        }
      }
    }
    for (int s = 0; s < 2; ++s){              // horizontal sources j0=j-1, j
      int j0 = j - 1 + s;
      if (j0 >= 0 && j0 <= WW-2){
        float v1 = GT[i*WW+j0], v2 = GT[i*WW+j0+1];
        int m = (v1 == 0.0f) || (v2 == 0.0f) || ((v1*v2) < 0.0f);
        if (m){
          float a1 = fabsf(v1), a2 = fabsf(v2);
          float den = (a1 + a2) + 1e-8f;
          float b = a1 / den;
          float j0f = (float)j0;
          float c = (v1 == 0.0f) ? j0f : ((v2 == 0.0f) ? (j0f + 1.0f) : (j0f + b));
          if ((int)floorf(c) == j){           // lands in this cell col
            float r = (float)i;
            float sg = (r*r) + (c*c);
            slot[cnt++] = make_float4(r, c, sg,
                            __int_as_float(NV + i*(WW-1) + j0));
          }
        }
      }
    }
    for (int s = cnt; s < SLOTS; ++s)         // sentinels: never win, never tie
      slot[s] = make_float4(0.0f, 0.0f, SENT_D, __int_as_float(SENT_J));
    cells[t*SLOTS+0] = slot[0]; cells[t*SLOTS+1] = slot[1];
    cells[t*SLOTS+2] = slot[2]; cells[t*SLOTS+3] = slot[3];
  } else if (t < NPIX + NC){                  // pred extraction
    int u = t - NPIX;
    float v1, v2, r, c;
    if (u < NV){
      int i0 = u / WW, j = u % WW;
      v1 = PR[i0*WW+j]; v2 = PR[(i0+1)*WW+j];
      float a1 = fabsf(v1), a2 = fabsf(v2);
      float den = (a1 + a2) + 1e-8f;
      float a = a1 / den;
      float i0f = (float)i0;
      r = (v1 == 0.0f) ? i0f : ((v2 == 0.0f) ? (i0f + 1.0f) : (i0f + a));
      c = (float)j;
    } else {
      int u2 = u - NV;
      int i = u2 / (WW-1), j0 = u2 % (WW-1);
      v1 = PR[i*WW+j0]; v2 = PR[i*WW+j0+1];
      float a1 = fabsf(v1), a2 = fabsf(v2);
      float den = (a1 + a2) + 1e-8f;
      float b = a1 / den;
      float j0f = (float)j0;
      c = (v1 == 0.0f) ? j0f : ((v2 == 0.0f) ? (j0f + 1.0f) : (j0f + b));
      r = (float)i;
    }
    int m = (v1 == 0.0f) || (v2 == 0.0f) || ((v1*v2) < 0.0f);
    float sp = (r*r) + (c*c);           // matches (pr_pts**2).sum(1) bits
    prQ[u] = make_float4(r, c, sp, __int_as_float(m));
  }
}

// ring offset for chebyshev ring R, perimeter index q in [0, 8R)
__device__ __forceinline__ void ring_off(int R, int q, int& dr, int& dc){
  int side = 2*R + 1;
  if (q < side){ dr = -R; dc = q - R; }
  else if (q < 2*side){ dr = R; dc = q - side - R; }
  else {
    int q2 = q - 2*side, half = side - 2;
    if (q2 < half){ dr = q2 - R + 1; dc = -R; }
    else          { dr = q2 - half - R + 1; dc = R; }
  }
}

// ---- K2: 16-lane-group-per-point NN, sentinel slots, packed point load ----
__global__ __launch_bounds__(256) void k_nndot(
    const float* __restrict__ PR, const float2* __restrict__ N2,
    const float4* __restrict__ prQ, const float4* __restrict__ cells,
    float* dotA, double* pvPart){
#pragma clang fp contract(off)
  int tid = threadIdx.x;
  int g = tid >> 4, l = tid & 15;      // 16 groups/block, 16 lanes/group
  int k = blockIdx.x*16 + g;           // grid is exactly NC/16 blocks
  float4 pq = prQ[k];                  // one broadcast load: r, c, sp, m
  float rp = pq.x, cp = pq.y, sp = pq.z;
  int m = __float_as_int(pq.w);
  // corner prefetch (group-uniform addresses)
  int fr = (int)floorf(rp), fc = (int)floorf(cp);
  int r0 = fr; if (r0 < 0) r0 = 0; if (r0 > HH-1) r0 = HH-1;
  int c0 = fc; if (c0 < 0) c0 = 0; if (c0 > WW-1) c0 = WW-1;
  int r1 = r0 + 1; if (r1 > HH-1) r1 = HH-1;
  int c1 = c0 + 1; if (c1 > WW-1) c1 = WW-1;
  float2 na = N2[r0*WW+c0], nb = N2[r0*WW+c1];
  float2 ncn = N2[r1*WW+c0], nd = N2[r1*WW+c1];
  float pa = PR[r0*WW+c0], pb = PR[r0*WW+c1];
  float pc = PR[r1*WW+c0], pd = PR[r1*WW+c1];
  float best = SENT_D, brg = 0.0f, bcg = 0.0f; int bjg = SENT_J;
  // phase 1: inner 5x5 (radius 2), cells l and l+16 per lane
  for (int idx = l; idx < 25; idx += 16){
    int ci = fr + idx/5 - 2, cj = fc + idx%5 - 2;
    if (ci >= 0 && ci < HH && cj >= 0 && cj < WW){
      const float4* cb = &cells[(ci*WW + cj)*SLOTS];
      for (int s = 0; s < SLOTS; ++s){        // unconditional: sentinels inert
        float4 gg = cb[s];
        float cross = fmaf(cp, gg.y, rp*gg.x);     // same bits as brute force
        float d2 = (sp + gg.z) - (2.0f*cross);
        d2 = fmaxf(d2, 0.0f);
        int jg = __float_as_int(gg.w);
        if ((d2 < best) || ((d2 == best) && (jg < bjg))){
          best = d2; bjg = jg; brg = gg.x; bcg = gg.y;
        }
      }
    }
  }
  for (int off = 8; off; off >>= 1){   // lex butterfly within 16-lane group
    float ob = __shfl_xor(best, off, 64);
    int   oj = __shfl_xor(bjg,  off, 64);
    float orr = __shfl_xor(brg, off, 64);
    float oc = __shfl_xor(bcg, off, 64);
    if ((ob < best) || ((ob == best) && (oj < bjg))){
      best = ob; bjg = oj; brg = orr; bcg = oc;
    }
  }
  // outside radius 2 true d2 > 4 (computed >= 4-6e-6): skip if best <= 3.9999
  if (best > 3.9999f){                 // group-uniform after reduce
    for (int q = l; q < 56; q += 16){  // rings 3 (24) + 4 (32)
      int dr2, dc2;
      if (q < 24) ring_off(3, q, dr2, dc2);
      else        ring_off(4, q-24, dr2, dc2);
      int ci = fr + dr2, cj = fc + dc2;
      if (ci >= 0 && ci < HH && cj >= 0 && cj < WW){
        const float4* cb = &cells[(ci*WW + cj)*SLOTS];
        for (int s = 0; s < SLOTS; ++s){
          float4 gg = cb[s];
          float cross = fmaf(cp, gg.y, rp*gg.x);
          float d2 = (sp + gg.z) - (2.0f*cross);
          d2 = fmaxf(d2, 0.0f);
          int jg = __float_as_int(gg.w);
          if ((d2 < best) || ((d2 == best) && (jg < bjg))){
            best = d2; bjg = jg; brg = gg.x; bcg = gg.y;
          }
        }
      }
    }
    for (int off = 8; off; off >>= 1){
      float ob = __shfl_xor(best, off, 64);
      int   oj = __shfl_xor(bjg,  off, 64);
      float orr = __shfl_xor(brg, off, 64);
      float oc = __shfl_xor(bcg, off, 64);
      if ((ob < best) || ((ob == best) && (oj < bjg))){
        best = ob; bjg = oj; brg = orr; bcg = oc;
      }
    }
  }
  // epilogue: all lanes of group redundantly (broadcast loads already done)
  float ar = rp - (float)r0, ac = cp - (float)c0;
  float omr = 1.0f - ar, omc = 1.0f - ac;
  float wa = omr*omc, wb = omr*ac, wc = ar*omc, wd = ar*ac;
  float nr = (((na.x*wa) + (nb.x*wb)) + (ncn.x*wc)) + (nd.x*wd);
  float nc = (((na.y*wa) + (nb.y*wb)) + (ncn.y*wc)) + (nd.y*wd);
  float nrm = sqrtf((nr*nr) + (nc*nc));
  float den = nrm + 1e-8f;
  float nru = nr / den, ncu = nc / den;
  float dr = brg - rp, dc = bcg - cp;  // winner coords carried in-register
  float dotv = (dr*nru) + (dc*ncu);
  int contrib = m && (best <= 9.0f);
  float vals = (((pa*wa) + (pb*wb)) + (pc*wc)) + (pd*wd);
  __shared__ float sdot[16];
  __shared__ double sb[16];
  if (l == 0){
    sdot[g] = contrib ? dotv : 0.0f;
    sb[g] = m ? (double)vals : 0.0;
  }
  __syncthreads();
  if (tid < 16)                        // coalesced: 16 consecutive k per block
    dotA[blockIdx.x*16 + tid] = sdot[tid];
  if (tid == 0){
    double acc = 0.0;
    for (int q = 0; q < 16; ++q) acc += sb[q];
    pvPart[blockIdx.x] = acc;
  }
}

// ---- K3: ordered scatter replication + fused last-block final reduction ---
__global__ __launch_bounds__(128) void k_pixfinal(
    const float* __restrict__ PR, const float4* __restrict__ prQ,
    const float* __restrict__ dotA, const double* __restrict__ pvPart,
    float* tmp, int* finCnt, float* out){
#pragma clang fp contract(off)
  int p = blockIdx.x*128 + threadIdx.x;   // exactly NPIX threads
  int i = p / WW, j = p % WW;
  float s = 0.0f;
  // pass1 vertical: wa = (1-ar) at (r0, j)
  for (int i0 = i-1; i0 <= i; ++i0){
    if (i0 < 0 || i0 > HH-2) continue;
    int k = i0*WW + j;
    float r = prQ[k].x;
    int r0 = (int)floorf(r);
    if (r0 == i){
      float ar = r - (float)r0;
      float w = 1.0f - ar;
      s = s + (dotA[k] * w);
    }
  }
  // pass1 horizontal: wa = (1-ac) at (i, c0)
  for (int j0 = j-1; j0 <= j; ++j0){
    if (j0 < 0 || j0 > WW-2) continue;
    int k = NV + i*(WW-1) + j0;
    float c = prQ[k].y;
    int c0 = (int)floorf(c);
    if (c0 == j){
      float ac = c - (float)c0;
      float w = 1.0f - ac;
      s = s + (dotA[k] * w);
    }
  }
  // pass2 horizontal: wb = ac at (i, c0+1)
  for (int j0 = j-2; j0 <= j-1; ++j0){
    if (j0 < 0 || j0 > WW-2) continue;
    int k = NV + i*(WW-1) + j0;
    float c = prQ[k].y;
    int c0 = (int)floorf(c);
    if (c0 == j-1){
      float ac = c - (float)c0;
      s = s + (dotA[k] * ac);
    }
  }
  // pass3 vertical: wc = ar at (r0+1, j)
  for (int i0 = i-2; i0 <= i-1; ++i0){
    if (i0 < 0 || i0 > HH-2) continue;
    int k = i0*WW + j;
    float r = prQ[k].x;
    int r0 = (int)floorf(r);
    if (r0 == i-1){
      float ar = r - (float)r0;
      s = s + (dotA[k] * ar);
    }
  }
  tmp[p] = PR[p] * s;
  // release tmp writes, count this block done
  __threadfence();
  __syncthreads();
  __shared__ int lastFlag;
  if (threadIdx.x == 0){
    int old = atomicAdd(finCnt, 1);      // device-scope
    lastFlag = (old == PBLK-1);
  }
  __syncthreads();
  if (!lastFlag) return;
  __threadfence();                       // acquire: see all blocks' tmp
  // numpy pairwise sum (128 leaves x 72, identical order) + pix double sum
  __shared__ float buf[128];
  __shared__ double dbuf[128];
  int t = threadIdx.x;
  const float4* a4 = (const float4*)(tmp + t*72);
  float4 x = a4[0], y = a4[1];
  float q0=x.x, q1=x.y, q2=x.z, q3=x.w, q4=y.x, q5=y.y, q6=y.z, q7=y.w;
  for (int i4 = 2; i4 < 18; i4 += 2){
    float4 u = a4[i4], v = a4[i4+1];
    q0 += u.x; q1 += u.y; q2 += u.z; q3 += u.w;
    q4 += v.x; q5 += v.y; q6 += v.z; q7 += v.w;
  }
  buf[t] = ((q0+q1)+(q2+q3)) + ((q4+q5)+(q6+q7));
  double pv = 0.0;
  for (int idx = t; idx < NBLK2; idx += 128) pv += pvPart[idx];
  dbuf[t] = pv;
  __syncthreads();
  for (int st = 1; st < 128; st <<= 1){
    if ((t & (2*st - 1)) == 0){
      buf[t]  = buf[t]  + buf[t+st];
      dbuf[t] = dbuf[t] + dbuf[t+st];
    }
    __syncthreads();
  }
  if (t == 0) out[0] = buf[0] + (float)dbuf[0];
}

extern "C" void kernel_launch(void* const* d_in, const int* in_sizes, int n_in,
                              void* d_out, int out_size, void* d_ws, size_t ws_size,
                              hipStream_t stream){
  const float* pred = (const float*)d_in[0];
  const float* gt   = (const float*)d_in[1];
  float* out = (float*)d_out;

  char* w = (char*)d_ws;
  float4* cells  = (float4*)w;                 w += (size_t)NCELL*SLOTS*sizeof(float4);
  float4* prQ    = (float4*)w;                 w += (size_t)NC*sizeof(float4);
  double* pvPart = (double*)w;                 w += (size_t)NBLK2*sizeof(double);
  float2* N2     = (float2*)w;                 w += (size_t)NPIX*sizeof(float2);
  float*  dotA   = (float*)w;                  w += (size_t)NC*sizeof(float);
  float*  tmp    = (float*)w;                  w += (size_t)NPIX*sizeof(float);
  int*    finCnt = (int*)w;

  k_prep<<<dim3(108), dim3(256), 0, stream>>>(pred, gt, N2, prQ, cells, finCnt);
  k_nndot<<<dim3(NBLK2), dim3(256), 0, stream>>>(pred, N2, prQ, cells,
                                                 dotA, pvPart);
  k_pixfinal<<<dim3(PBLK), dim3(128), 0, stream>>>(pred, prQ, dotA, pvPart,
                                                   tmp, finCnt, out);
}